// Round 14
// baseline (20118.871 us; speedup 1.0000x reference)
//
#include <hip/hip_runtime.h>

#define T_SEQ 8192
#define HDIM  2048
#define EDIM  2048
#define RBLK  64                      // recurrence blocks (forced by VGPR capacity)
#define ROWS_PER_BLK (HDIM / RBLK)    // 32 rows/block, 4 rows/wave

typedef unsigned long long u64;
typedef unsigned int u32;
typedef __attribute__((ext_vector_type(4))) unsigned int u32x4;
typedef __attribute__((ext_vector_type(4))) float f32x4;

// ONE 16B agent-coherent load + drain: covers a thread's entire 4-row share
// of the bf16-packed h broadcast (R13 needed two of these for f32).
__device__ inline void poll_one(const u64* p, u32x4& a) {
    asm volatile("global_load_dwordx4 %0, %1, off sc1\n\ts_waitcnt vmcnt(0)"
                 : "=v"(a) : "v"(p) : "memory");
}

// Non-rematerializable 16B load: result MUST live in registers (asm output).
__device__ inline f32x4 ld_w16(const float* p) {
    f32x4 r;
    asm volatile("global_load_dwordx4 %0, %1, off" : "=v"(r) : "v"(p));
    return r;
}

// tanh via e^{2z}: clamp +-15, exp2, rcp (validated R8/R9: absmax unchanged)
__device__ inline float fast_tanh(float z) {
    float zc = fminf(fmaxf(z, -15.f), 15.f);
    float zs = zc * 2.88539008177792681f;   // 2*log2(e)
    float ez; asm("v_exp_f32 %0, %1" : "=v"(ez) : "v"(zs));
    float rc; float ezp = ez + 1.f;
    asm("v_rcp_f32 %0, %1" : "=v"(rc) : "v"(ezp));
    return (ez - 1.f) * rc;
}

// ---------------------------------------------------------------------------
// 128x128-tile GEMM (NT): C[m][n] = sum_k A[m][k]*B[n][k] + bias[n]  (R13)
// ---------------------------------------------------------------------------
__global__ __launch_bounds__(256) void gemm128_nt_bias(
    const float* __restrict__ A, const float* __restrict__ B,
    const float* __restrict__ bias, float* __restrict__ C,
    int M, int N, int K)
{
    __shared__ float As[16][128 + 4];
    __shared__ float Bs[16][128 + 4];

    const int tid = threadIdx.x;
    const int tx = tid & 15;
    const int ty = tid >> 4;
    const int m0 = blockIdx.y * 128;
    const int n0 = blockIdx.x * 128;

    float acc[8][8] = {};

    for (int kk = 0; kk < K; kk += 16) {
        #pragma unroll
        for (int p = 0; p < 2; ++p) {
            int idx = p * 256 + tid;
            int r  = idx >> 2;
            int cb = (idx & 3) * 4;
            float4 va = *(const float4*)&A[(size_t)(m0 + r) * K + kk + cb];
            As[cb + 0][r] = va.x; As[cb + 1][r] = va.y;
            As[cb + 2][r] = va.z; As[cb + 3][r] = va.w;
            float4 vb = *(const float4*)&B[(size_t)(n0 + r) * K + kk + cb];
            Bs[cb + 0][r] = vb.x; Bs[cb + 1][r] = vb.y;
            Bs[cb + 2][r] = vb.z; Bs[cb + 3][r] = vb.w;
        }
        __syncthreads();
        #pragma unroll
        for (int k = 0; k < 16; ++k) {
            float4 a0 = *(const float4*)&As[k][ty * 8];
            float4 a1 = *(const float4*)&As[k][ty * 8 + 4];
            float4 b0 = *(const float4*)&Bs[k][tx * 8];
            float4 b1 = *(const float4*)&Bs[k][tx * 8 + 4];
            float av[8] = {a0.x, a0.y, a0.z, a0.w, a1.x, a1.y, a1.z, a1.w};
            float bv[8] = {b0.x, b0.y, b0.z, b0.w, b1.x, b1.y, b1.z, b1.w};
            #pragma unroll
            for (int i = 0; i < 8; ++i)
                #pragma unroll
                for (int j = 0; j < 8; ++j)
                    acc[i][j] = fmaf(av[i], bv[j], acc[i][j]);
        }
        __syncthreads();
    }

    float4 bb0 = *(const float4*)&bias[n0 + tx * 8];
    float4 bb1 = *(const float4*)&bias[n0 + tx * 8 + 4];
    float bv[8] = {bb0.x, bb0.y, bb0.z, bb0.w, bb1.x, bb1.y, bb1.z, bb1.w};
    #pragma unroll
    for (int i = 0; i < 8; ++i) {
        float4 o0, o1;
        o0.x = acc[i][0] + bv[0]; o0.y = acc[i][1] + bv[1];
        o0.z = acc[i][2] + bv[2]; o0.w = acc[i][3] + bv[3];
        o1.x = acc[i][4] + bv[4]; o1.y = acc[i][5] + bv[5];
        o1.z = acc[i][6] + bv[6]; o1.w = acc[i][7] + bv[7];
        float* cp = &C[(size_t)(m0 + ty * 8 + i) * N + n0 + tx * 8];
        *(float4*)cp = o0;
        *(float4*)(cp + 4) = o1;
    }
}

// ---------------------------------------------------------------------------
// Same 128x128 GEMM, TRANSPOSED output: Ct[n][m] (xpT: 16 steps per line).
// ---------------------------------------------------------------------------
__global__ __launch_bounds__(256) void gemm128_nt_bias_tc(
    const float* __restrict__ A, const float* __restrict__ B,
    const float* __restrict__ bias, float* __restrict__ Ct,
    int M, int N, int K)
{
    __shared__ float As[16][128 + 4];
    __shared__ float Bs[16][128 + 4];

    const int tid = threadIdx.x;
    const int tx = tid & 15;
    const int ty = tid >> 4;
    const int m0 = blockIdx.y * 128;
    const int n0 = blockIdx.x * 128;

    float acc[8][8] = {};

    for (int kk = 0; kk < K; kk += 16) {
        #pragma unroll
        for (int p = 0; p < 2; ++p) {
            int idx = p * 256 + tid;
            int r  = idx >> 2;
            int cb = (idx & 3) * 4;
            float4 va = *(const float4*)&A[(size_t)(m0 + r) * K + kk + cb];
            As[cb + 0][r] = va.x; As[cb + 1][r] = va.y;
            As[cb + 2][r] = va.z; As[cb + 3][r] = va.w;
            float4 vb = *(const float4*)&B[(size_t)(n0 + r) * K + kk + cb];
            Bs[cb + 0][r] = vb.x; Bs[cb + 1][r] = vb.y;
            Bs[cb + 2][r] = vb.z; Bs[cb + 3][r] = vb.w;
        }
        __syncthreads();
        #pragma unroll
        for (int k = 0; k < 16; ++k) {
            float4 a0 = *(const float4*)&As[k][ty * 8];
            float4 a1 = *(const float4*)&As[k][ty * 8 + 4];
            float4 b0 = *(const float4*)&Bs[k][tx * 8];
            float4 b1 = *(const float4*)&Bs[k][tx * 8 + 4];
            float av[8] = {a0.x, a0.y, a0.z, a0.w, a1.x, a1.y, a1.z, a1.w};
            float bv[8] = {b0.x, b0.y, b0.z, b0.w, b1.x, b1.y, b1.z, b1.w};
            #pragma unroll
            for (int i = 0; i < 8; ++i)
                #pragma unroll
                for (int j = 0; j < 8; ++j)
                    acc[i][j] = fmaf(av[i], bv[j], acc[i][j]);
        }
        __syncthreads();
    }

    #pragma unroll
    for (int j = 0; j < 8; ++j) {
        float bb = bias[n0 + tx * 8 + j];
        float4 o0, o1;
        o0.x = acc[0][j] + bb; o0.y = acc[1][j] + bb;
        o0.z = acc[2][j] + bb; o0.w = acc[3][j] + bb;
        o1.x = acc[4][j] + bb; o1.y = acc[5][j] + bb;
        o1.z = acc[6][j] + bb; o1.w = acc[7][j] + bb;
        float* cp = &Ct[(size_t)(n0 + tx * 8 + j) * M + m0 + ty * 8];
        *(float4*)cp = o0;
        *(float4*)(cp + 4) = o1;
    }
}

// ---------------------------------------------------------------------------
// Recurrence — R9/R13 structure with bf16-PACKED h exchange.
//   hbuf[2][1024] u64: word w = (tag32<<32) | (bf16 h_{2w+1}<<16) | bf16 h_{2w}.
//   Reader thread tid polls ONE dwordx4 (2 words = its 4 rows 4tid..4tid+3):
//   32K requests/step & 0.5MB/step vs R13's 65K/1MB — halves fabric load.
//   Unpack = shl/and per value; staged to LDS as f32, dot/fold unchanged.
//   Writers: lanes 0-3 compute f32 hn (stored f32 to Hs), RNE-round to bf16,
//   lane pairs (0,1) and (2,3) merge via one shfl_xor; lanes 0,2 store the
//   two packed words with relaxed agent-scope atomic exchange.
//   Overwrite safety unchanged: a wave's tag-(t+1) store value-depends
//   (through hsm + barrier) on ALL threads' tag-t polls.
//   Numerics: bf16 h only perturbs the recurrent matvec input (|dz|~0.03);
//   pre-activations sigma~26 -> tanh saturated, error damped; Hs/logits f32.
// ---------------------------------------------------------------------------
__global__ __launch_bounds__(512, 1) void rnn_recurrence(
    const float* __restrict__ Wh, const float* __restrict__ xpT,
    float* __restrict__ Hs, u64* __restrict__ hbuf, int T)
{
    const int tid  = threadIdx.x;
    const int lane = tid & 63;
    const int wid  = tid >> 6;                              // 0..7
    const int r0   = blockIdx.x * ROWS_PER_BLK + wid * 4;   // wave's first row

    const float* wr0 = Wh + (size_t)(r0 + 0) * HDIM + lane * 4;
    const float* wr1 = Wh + (size_t)(r0 + 1) * HDIM + lane * 4;
    const float* wr2 = Wh + (size_t)(r0 + 2) * HDIM + lane * 4;
    const float* wr3 = Wh + (size_t)(r0 + 3) * HDIM + lane * 4;

    f32x4 w00 = ld_w16(wr0 + 0*256), w01 = ld_w16(wr0 + 1*256), w02 = ld_w16(wr0 + 2*256), w03 = ld_w16(wr0 + 3*256);
    f32x4 w04 = ld_w16(wr0 + 4*256), w05 = ld_w16(wr0 + 5*256), w06 = ld_w16(wr0 + 6*256), w07 = ld_w16(wr0 + 7*256);
    f32x4 w10 = ld_w16(wr1 + 0*256), w11 = ld_w16(wr1 + 1*256), w12 = ld_w16(wr1 + 2*256), w13 = ld_w16(wr1 + 3*256);
    f32x4 w14 = ld_w16(wr1 + 4*256), w15 = ld_w16(wr1 + 5*256), w16 = ld_w16(wr1 + 6*256), w17 = ld_w16(wr1 + 7*256);
    f32x4 w20 = ld_w16(wr2 + 0*256), w21 = ld_w16(wr2 + 1*256), w22 = ld_w16(wr2 + 2*256), w23 = ld_w16(wr2 + 3*256);
    f32x4 w24 = ld_w16(wr2 + 4*256), w25 = ld_w16(wr2 + 5*256), w26 = ld_w16(wr2 + 6*256), w27 = ld_w16(wr2 + 7*256);
    f32x4 w30 = ld_w16(wr3 + 0*256), w31 = ld_w16(wr3 + 1*256), w32 = ld_w16(wr3 + 2*256), w33 = ld_w16(wr3 + 3*256);
    f32x4 w34 = ld_w16(wr3 + 4*256), w35 = ld_w16(wr3 + 5*256), w36 = ld_w16(wr3 + 6*256), w37 = ld_w16(wr3 + 7*256);
    asm volatile("s_waitcnt vmcnt(0)" ::: "memory");

    __shared__ float hsm[HDIM];

    for (int t = 0; t < T; ++t) {
        float xq = 0.f;
        if (lane < 4) xq = xpT[(size_t)(r0 + lane) * T + t];

        float sv = 0.f;
        if (t > 0) {
            const u64* hb = hbuf + (size_t)(t & 1) * 1024 + 2 * tid;
            const unsigned tg = (unsigned)t;

            u32x4 a;
            poll_one(hb, a);
            while ((a.y != tg) | (a.w != tg))
                poll_one(hb, a);

            // unpack 4 bf16 -> f32, stage rows 4tid..4tid+3
            float4 hv;
            hv.x = __uint_as_float(a.x << 16);
            hv.y = __uint_as_float(a.x & 0xffff0000u);
            hv.z = __uint_as_float(a.z << 16);
            hv.w = __uint_as_float(a.z & 0xffff0000u);
            ((float4*)hsm)[tid] = hv;
            __syncthreads();

            float s0 = 0.f, s1 = 0.f, s2 = 0.f, s3 = 0.f;
            #define RNN_STEP(IDX, WA, WB, WC, WD)                                   \
            {   float4 h4 = ((const float4*)hsm)[(IDX) * 64 + lane];                \
                s0 = fmaf(WA.x, h4.x, s0); s0 = fmaf(WA.y, h4.y, s0);               \
                s0 = fmaf(WA.z, h4.z, s0); s0 = fmaf(WA.w, h4.w, s0);               \
                s1 = fmaf(WB.x, h4.x, s1); s1 = fmaf(WB.y, h4.y, s1);               \
                s1 = fmaf(WB.z, h4.z, s1); s1 = fmaf(WB.w, h4.w, s1);               \
                s2 = fmaf(WC.x, h4.x, s2); s2 = fmaf(WC.y, h4.y, s2);               \
                s2 = fmaf(WC.z, h4.z, s2); s2 = fmaf(WC.w, h4.w, s2);               \
                s3 = fmaf(WD.x, h4.x, s3); s3 = fmaf(WD.y, h4.y, s3);               \
                s3 = fmaf(WD.z, h4.z, s3); s3 = fmaf(WD.w, h4.w, s3); }
            RNN_STEP(0, w00, w10, w20, w30)
            RNN_STEP(1, w01, w11, w21, w31)
            RNN_STEP(2, w02, w12, w22, w32)
            RNN_STEP(3, w03, w13, w23, w33)
            RNN_STEP(4, w04, w14, w24, w34)
            RNN_STEP(5, w05, w15, w25, w35)
            RNN_STEP(6, w06, w16, w26, w36)
            RNN_STEP(7, w07, w17, w27, w37)
            #undef RNN_STEP

            float fa = (lane & 1) ? s1 : s0;
            float fb = (lane & 1) ? s0 : s1;
            fa += __shfl_xor(fb, 1);
            float fc = (lane & 1) ? s3 : s2;
            float fd = (lane & 1) ? s2 : s3;
            fc += __shfl_xor(fd, 1);
            float fe = (lane & 2) ? fc : fa;
            float ff = (lane & 2) ? fa : fc;
            fe += __shfl_xor(ff, 2);
            #pragma unroll
            for (int off = 4; off < 64; off <<= 1) fe += __shfl_xor(fe, off);
            sv = fe;
        }

        // lanes 0-3 hold valid sums; compute f32 h, round to bf16 (RNE)
        float hn = fast_tanh(sv + xq);
        unsigned ub = __float_as_uint(hn);
        unsigned b16 = (ub + 0x7fffu + ((ub >> 16) & 1u)) >> 16;
        unsigned partner = (unsigned)__shfl_xor((int)b16, 1);   // lane0<-1, lane2<-3

        if (lane < 4) {
            if ((lane & 1) == 0) {
                // word (r0>>1)+(lane>>1): rows r0+lane (low) and r0+lane+1 (high)
                u64 pk = ((u64)(unsigned)(t + 1) << 32)
                       | ((u64)(partner & 0xffffu) << 16) | (u64)(b16 & 0xffffu);
                (void)__hip_atomic_exchange(
                    &hbuf[(size_t)((t + 1) & 1) * 1024 + (r0 >> 1) + (lane >> 1)],
                    pk, __ATOMIC_RELAXED, __HIP_MEMORY_SCOPE_AGENT);
            }
            Hs[(size_t)t * HDIM + r0 + lane] = hn;   // f32, consumed by GEMM-3
        }
    }
}

// ---------------------------------------------------------------------------
// Row softmax over EDIM=2048: one block (256 threads) per row.
// ---------------------------------------------------------------------------
__global__ __launch_bounds__(256) void softmax_rows(
    const float* __restrict__ logits, float* __restrict__ out)
{
    const int row = blockIdx.x;
    const float4* in4 = (const float4*)(logits + (size_t)row * EDIM);
    float4* out4 = (float4*)(out + (size_t)row * EDIM);

    float4 v0 = in4[threadIdx.x];
    float4 v1 = in4[threadIdx.x + 256];

    float m = fmaxf(fmaxf(fmaxf(v0.x, v0.y), fmaxf(v0.z, v0.w)),
                    fmaxf(fmaxf(v1.x, v1.y), fmaxf(v1.z, v1.w)));
    #pragma unroll
    for (int off = 32; off > 0; off >>= 1) m = fmaxf(m, __shfl_xor(m, off));

    __shared__ float red[4];
    if ((threadIdx.x & 63) == 0) red[threadIdx.x >> 6] = m;
    __syncthreads();
    m = fmaxf(fmaxf(red[0], red[1]), fmaxf(red[2], red[3]));
    __syncthreads();

    float e[8];
    e[0] = expf(v0.x - m); e[1] = expf(v0.y - m);
    e[2] = expf(v0.z - m); e[3] = expf(v0.w - m);
    e[4] = expf(v1.x - m); e[5] = expf(v1.y - m);
    e[6] = expf(v1.z - m); e[7] = expf(v1.w - m);

    float s = e[0] + e[1] + e[2] + e[3] + e[4] + e[5] + e[6] + e[7];
    #pragma unroll
    for (int off = 32; off > 0; off >>= 1) s += __shfl_xor(s, off);
    if ((threadIdx.x & 63) == 0) red[threadIdx.x >> 6] = s;
    __syncthreads();
    s = red[0] + red[1] + red[2] + red[3];

    float inv = 1.0f / s;
    out4[threadIdx.x]       = make_float4(e[0] * inv, e[1] * inv, e[2] * inv, e[3] * inv);
    out4[threadIdx.x + 256] = make_float4(e[4] * inv, e[5] * inv, e[6] * inv, e[7] * inv);
}

__global__ void copy_vec(const float* __restrict__ src, float* __restrict__ dst, int n)
{
    int i = blockIdx.x * blockDim.x + threadIdx.x;
    if (i < n) dst[i] = src[i];
}

// ---------------------------------------------------------------------------
extern "C" void kernel_launch(void* const* d_in, const int* in_sizes, int n_in,
                              void* d_out, int out_size, void* d_ws, size_t ws_size,
                              hipStream_t stream)
{
    const float* x  = (const float*)d_in[0];   // [T_SEQ][EDIM]
    const float* Wh = (const float*)d_in[1];   // [HDIM][HDIM]
    const float* Wx = (const float*)d_in[2];   // [HDIM][EDIM]
    const float* Wy = (const float*)d_in[3];   // [EDIM][HDIM]
    const float* Bh = (const float*)d_in[4];   // [HDIM]
    const float* By = (const float*)d_in[5];   // [EDIM]

    float* out    = (float*)d_out;
    float* hfinal = out;                 // [HDIM]
    float* hs     = out + HDIM;          // [T_SEQ][HDIM]: holds hs, then probs

    float* xpT  = (float*)d_ws;                                   // [HDIM][T_SEQ]
    u64*   hbuf = (u64*)((char*)d_ws + (size_t)T_SEQ * HDIM * 4); // [2][1024] packed
    float* logits = xpT;                 // reuse (xpT dead after recurrence)

    // clear tagged h buffers so replays never see stale tags
    hipMemsetAsync(hbuf, 0, 2 * 1024 * sizeof(u64), stream);

    // Phase 1: xpT = (x @ Wx^T + Bh)^T   -> [HDIM][T_SEQ]
    gemm128_nt_bias_tc<<<dim3(HDIM / 128, T_SEQ / 128), 256, 0, stream>>>(
        x, Wx, Bh, xpT, T_SEQ, HDIM, EDIM);

    // Phase 2: recurrence — cooperative launch only to guarantee co-residency
    int T = T_SEQ;
    const float* xpT_c = xpT;
    void* args[] = {(void*)&Wh, (void*)&xpT_c, (void*)&hs, (void*)&hbuf, (void*)&T};
    hipLaunchCooperativeKernel((void*)rnn_recurrence, dim3(RBLK), dim3(512),
                               args, 0, stream);

    // Phase 3: logits = hs @ Wy^T + By   (normal [T][E] layout)
    gemm128_nt_bias<<<dim3(EDIM / 128, T_SEQ / 128), 256, 0, stream>>>(
        hs, Wy, By, logits, T_SEQ, EDIM, HDIM);

    // Phase 4: h_final = hs[T-1] (before softmax overwrites hs region)
    copy_vec<<<dim3(HDIM / 256), 256, 0, stream>>>(
        hs + (size_t)(T_SEQ - 1) * HDIM, hfinal, HDIM);

    // Phase 5: softmax rows: logits (ws) -> output region of d_out
    softmax_rows<<<dim3(T_SEQ), 256, 0, stream>>>(logits, hs);
}

// Round 15
// 19614.958 us; speedup vs baseline: 1.0257x; 1.0257x over previous
//
#include <hip/hip_runtime.h>

#define T_SEQ 8192
#define HDIM  2048
#define EDIM  2048
#define RBLK  64                      // recurrence blocks (forced by VGPR capacity)
#define ROWS_PER_BLK (HDIM / RBLK)    // 32 rows/block, 4 rows/wave
#define HB_STRIDE 4096                // u64s per buffer: 512 granules x 64B = 32KB

typedef unsigned long long u64;
typedef unsigned int u32;
typedef __attribute__((ext_vector_type(4))) unsigned int u32x4;
typedef __attribute__((ext_vector_type(4))) float f32x4;

// ONE 16B agent-coherent load + drain (thread's whole 4-row share, bf16-packed)
__device__ inline void poll_one(const u64* p, u32x4& a) {
    asm volatile("global_load_dwordx4 %0, %1, off sc1\n\ts_waitcnt vmcnt(0)"
                 : "=v"(a) : "v"(p) : "memory");
}

// Non-rematerializable 16B load: result MUST live in registers (asm output).
__device__ inline f32x4 ld_w16(const float* p) {
    f32x4 r;
    asm volatile("global_load_dwordx4 %0, %1, off" : "=v"(r) : "v"(p));
    return r;
}

// tanh via e^{2z}: clamp +-15, exp2, rcp (validated R8/R9: absmax unchanged)
__device__ inline float fast_tanh(float z) {
    float zc = fminf(fmaxf(z, -15.f), 15.f);
    float zs = zc * 2.88539008177792681f;   // 2*log2(e)
    float ez; asm("v_exp_f32 %0, %1" : "=v"(ez) : "v"(zs));
    float rc; float ezp = ez + 1.f;
    asm("v_rcp_f32 %0, %1" : "=v"(rc) : "v"(ezp));
    return (ez - 1.f) * rc;
}

// ---------------------------------------------------------------------------
// 128x128-tile GEMM (NT): C[m][n] = sum_k A[m][k]*B[n][k] + bias[n]  (R13)
// ---------------------------------------------------------------------------
__global__ __launch_bounds__(256) void gemm128_nt_bias(
    const float* __restrict__ A, const float* __restrict__ B,
    const float* __restrict__ bias, float* __restrict__ C,
    int M, int N, int K)
{
    __shared__ float As[16][128 + 4];
    __shared__ float Bs[16][128 + 4];

    const int tid = threadIdx.x;
    const int tx = tid & 15;
    const int ty = tid >> 4;
    const int m0 = blockIdx.y * 128;
    const int n0 = blockIdx.x * 128;

    float acc[8][8] = {};

    for (int kk = 0; kk < K; kk += 16) {
        #pragma unroll
        for (int p = 0; p < 2; ++p) {
            int idx = p * 256 + tid;
            int r  = idx >> 2;
            int cb = (idx & 3) * 4;
            float4 va = *(const float4*)&A[(size_t)(m0 + r) * K + kk + cb];
            As[cb + 0][r] = va.x; As[cb + 1][r] = va.y;
            As[cb + 2][r] = va.z; As[cb + 3][r] = va.w;
            float4 vb = *(const float4*)&B[(size_t)(n0 + r) * K + kk + cb];
            Bs[cb + 0][r] = vb.x; Bs[cb + 1][r] = vb.y;
            Bs[cb + 2][r] = vb.z; Bs[cb + 3][r] = vb.w;
        }
        __syncthreads();
        #pragma unroll
        for (int k = 0; k < 16; ++k) {
            float4 a0 = *(const float4*)&As[k][ty * 8];
            float4 a1 = *(const float4*)&As[k][ty * 8 + 4];
            float4 b0 = *(const float4*)&Bs[k][tx * 8];
            float4 b1 = *(const float4*)&Bs[k][tx * 8 + 4];
            float av[8] = {a0.x, a0.y, a0.z, a0.w, a1.x, a1.y, a1.z, a1.w};
            float bv[8] = {b0.x, b0.y, b0.z, b0.w, b1.x, b1.y, b1.z, b1.w};
            #pragma unroll
            for (int i = 0; i < 8; ++i)
                #pragma unroll
                for (int j = 0; j < 8; ++j)
                    acc[i][j] = fmaf(av[i], bv[j], acc[i][j]);
        }
        __syncthreads();
    }

    float4 bb0 = *(const float4*)&bias[n0 + tx * 8];
    float4 bb1 = *(const float4*)&bias[n0 + tx * 8 + 4];
    float bv[8] = {bb0.x, bb0.y, bb0.z, bb0.w, bb1.x, bb1.y, bb1.z, bb1.w};
    #pragma unroll
    for (int i = 0; i < 8; ++i) {
        float4 o0, o1;
        o0.x = acc[i][0] + bv[0]; o0.y = acc[i][1] + bv[1];
        o0.z = acc[i][2] + bv[2]; o0.w = acc[i][3] + bv[3];
        o1.x = acc[i][4] + bv[4]; o1.y = acc[i][5] + bv[5];
        o1.z = acc[i][6] + bv[6]; o1.w = acc[i][7] + bv[7];
        float* cp = &C[(size_t)(m0 + ty * 8 + i) * N + n0 + tx * 8];
        *(float4*)cp = o0;
        *(float4*)(cp + 4) = o1;
    }
}

// ---------------------------------------------------------------------------
// Same 128x128 GEMM, TRANSPOSED output: Ct[n][m] (xpT: 16 steps per line).
// ---------------------------------------------------------------------------
__global__ __launch_bounds__(256) void gemm128_nt_bias_tc(
    const float* __restrict__ A, const float* __restrict__ B,
    const float* __restrict__ bias, float* __restrict__ Ct,
    int M, int N, int K)
{
    __shared__ float As[16][128 + 4];
    __shared__ float Bs[16][128 + 4];

    const int tid = threadIdx.x;
    const int tx = tid & 15;
    const int ty = tid >> 4;
    const int m0 = blockIdx.y * 128;
    const int n0 = blockIdx.x * 128;

    float acc[8][8] = {};

    for (int kk = 0; kk < K; kk += 16) {
        #pragma unroll
        for (int p = 0; p < 2; ++p) {
            int idx = p * 256 + tid;
            int r  = idx >> 2;
            int cb = (idx & 3) * 4;
            float4 va = *(const float4*)&A[(size_t)(m0 + r) * K + kk + cb];
            As[cb + 0][r] = va.x; As[cb + 1][r] = va.y;
            As[cb + 2][r] = va.z; As[cb + 3][r] = va.w;
            float4 vb = *(const float4*)&B[(size_t)(n0 + r) * K + kk + cb];
            Bs[cb + 0][r] = vb.x; Bs[cb + 1][r] = vb.y;
            Bs[cb + 2][r] = vb.z; Bs[cb + 3][r] = vb.w;
        }
        __syncthreads();
        #pragma unroll
        for (int k = 0; k < 16; ++k) {
            float4 a0 = *(const float4*)&As[k][ty * 8];
            float4 a1 = *(const float4*)&As[k][ty * 8 + 4];
            float4 b0 = *(const float4*)&Bs[k][tx * 8];
            float4 b1 = *(const float4*)&Bs[k][tx * 8 + 4];
            float av[8] = {a0.x, a0.y, a0.z, a0.w, a1.x, a1.y, a1.z, a1.w};
            float bv[8] = {b0.x, b0.y, b0.z, b0.w, b1.x, b1.y, b1.z, b1.w};
            #pragma unroll
            for (int i = 0; i < 8; ++i)
                #pragma unroll
                for (int j = 0; j < 8; ++j)
                    acc[i][j] = fmaf(av[i], bv[j], acc[i][j]);
        }
        __syncthreads();
    }

    #pragma unroll
    for (int j = 0; j < 8; ++j) {
        float bb = bias[n0 + tx * 8 + j];
        float4 o0, o1;
        o0.x = acc[0][j] + bb; o0.y = acc[1][j] + bb;
        o0.z = acc[2][j] + bb; o0.w = acc[3][j] + bb;
        o1.x = acc[4][j] + bb; o1.y = acc[5][j] + bb;
        o1.z = acc[6][j] + bb; o1.w = acc[7][j] + bb;
        float* cp = &Ct[(size_t)(n0 + tx * 8 + j) * M + m0 + ty * 8];
        *(float4*)cp = o0;
        *(float4*)(cp + 4) = o1;
    }
}

// ---------------------------------------------------------------------------
// Recurrence — bf16-packed h exchange, LINE-PADDED granules (R15).
//   hbuf[2][HB_STRIDE] u64. Granule g (g=0..511) at u64 offset g*8 (64B line):
//   word0 = (tag<<32)|(bf16 h_{4g+1}<<16)|bf16 h_{4g},
//   word1 = (tag<<32)|(bf16 h_{4g+3}<<16)|bf16 h_{4g+2}; 48B pad.
//   Reader thread tid polls ONE dwordx4 at granule tid (its rows 4tid..+3).
//   Per 64B line: 64 pollers (1/block) + 2 writer xchgs — 4x less line
//   pressure than R13 (128+8) and R14 (256+8). R14's regression isolated
//   per-line L3-slice contention as the real cost, not bytes/requests.
//   Writers: wave wid of block b owns granule g = b*8+wid; lanes 0,2 store
//   word (lane>>1) after merging partner bf16 via shfl_xor(,1).
//   Overwrite safety unchanged: a wave's tag-(t+1) store value-depends
//   (through hsm + barrier) on ALL threads' tag-t polls.
// ---------------------------------------------------------------------------
__global__ __launch_bounds__(512, 1) void rnn_recurrence(
    const float* __restrict__ Wh, const float* __restrict__ xpT,
    float* __restrict__ Hs, u64* __restrict__ hbuf, int T)
{
    const int tid  = threadIdx.x;
    const int lane = tid & 63;
    const int wid  = tid >> 6;                              // 0..7
    const int r0   = blockIdx.x * ROWS_PER_BLK + wid * 4;   // wave's first row

    const float* wr0 = Wh + (size_t)(r0 + 0) * HDIM + lane * 4;
    const float* wr1 = Wh + (size_t)(r0 + 1) * HDIM + lane * 4;
    const float* wr2 = Wh + (size_t)(r0 + 2) * HDIM + lane * 4;
    const float* wr3 = Wh + (size_t)(r0 + 3) * HDIM + lane * 4;

    f32x4 w00 = ld_w16(wr0 + 0*256), w01 = ld_w16(wr0 + 1*256), w02 = ld_w16(wr0 + 2*256), w03 = ld_w16(wr0 + 3*256);
    f32x4 w04 = ld_w16(wr0 + 4*256), w05 = ld_w16(wr0 + 5*256), w06 = ld_w16(wr0 + 6*256), w07 = ld_w16(wr0 + 7*256);
    f32x4 w10 = ld_w16(wr1 + 0*256), w11 = ld_w16(wr1 + 1*256), w12 = ld_w16(wr1 + 2*256), w13 = ld_w16(wr1 + 3*256);
    f32x4 w14 = ld_w16(wr1 + 4*256), w15 = ld_w16(wr1 + 5*256), w16 = ld_w16(wr1 + 6*256), w17 = ld_w16(wr1 + 7*256);
    f32x4 w20 = ld_w16(wr2 + 0*256), w21 = ld_w16(wr2 + 1*256), w22 = ld_w16(wr2 + 2*256), w23 = ld_w16(wr2 + 3*256);
    f32x4 w24 = ld_w16(wr2 + 4*256), w25 = ld_w16(wr2 + 5*256), w26 = ld_w16(wr2 + 6*256), w27 = ld_w16(wr2 + 7*256);
    f32x4 w30 = ld_w16(wr3 + 0*256), w31 = ld_w16(wr3 + 1*256), w32 = ld_w16(wr3 + 2*256), w33 = ld_w16(wr3 + 3*256);
    f32x4 w34 = ld_w16(wr3 + 4*256), w35 = ld_w16(wr3 + 5*256), w36 = ld_w16(wr3 + 6*256), w37 = ld_w16(wr3 + 7*256);
    asm volatile("s_waitcnt vmcnt(0)" ::: "memory");

    __shared__ float hsm[HDIM];

    for (int t = 0; t < T; ++t) {
        float xq = 0.f;
        if (lane < 4) xq = xpT[(size_t)(r0 + lane) * T + t];

        float sv = 0.f;
        if (t > 0) {
            const u64* hb = hbuf + (size_t)(t & 1) * HB_STRIDE + (size_t)tid * 8;
            const unsigned tg = (unsigned)t;

            u32x4 a;
            poll_one(hb, a);
            while ((a.y != tg) | (a.w != tg))
                poll_one(hb, a);

            // unpack 4 bf16 -> f32, stage rows 4tid..4tid+3
            float4 hv;
            hv.x = __uint_as_float(a.x << 16);
            hv.y = __uint_as_float(a.x & 0xffff0000u);
            hv.z = __uint_as_float(a.z << 16);
            hv.w = __uint_as_float(a.z & 0xffff0000u);
            ((float4*)hsm)[tid] = hv;
            __syncthreads();

            float s0 = 0.f, s1 = 0.f, s2 = 0.f, s3 = 0.f;
            #define RNN_STEP(IDX, WA, WB, WC, WD)                                   \
            {   float4 h4 = ((const float4*)hsm)[(IDX) * 64 + lane];                \
                s0 = fmaf(WA.x, h4.x, s0); s0 = fmaf(WA.y, h4.y, s0);               \
                s0 = fmaf(WA.z, h4.z, s0); s0 = fmaf(WA.w, h4.w, s0);               \
                s1 = fmaf(WB.x, h4.x, s1); s1 = fmaf(WB.y, h4.y, s1);               \
                s1 = fmaf(WB.z, h4.z, s1); s1 = fmaf(WB.w, h4.w, s1);               \
                s2 = fmaf(WC.x, h4.x, s2); s2 = fmaf(WC.y, h4.y, s2);               \
                s2 = fmaf(WC.z, h4.z, s2); s2 = fmaf(WC.w, h4.w, s2);               \
                s3 = fmaf(WD.x, h4.x, s3); s3 = fmaf(WD.y, h4.y, s3);               \
                s3 = fmaf(WD.z, h4.z, s3); s3 = fmaf(WD.w, h4.w, s3); }
            RNN_STEP(0, w00, w10, w20, w30)
            RNN_STEP(1, w01, w11, w21, w31)
            RNN_STEP(2, w02, w12, w22, w32)
            RNN_STEP(3, w03, w13, w23, w33)
            RNN_STEP(4, w04, w14, w24, w34)
            RNN_STEP(5, w05, w15, w25, w35)
            RNN_STEP(6, w06, w16, w26, w36)
            RNN_STEP(7, w07, w17, w27, w37)
            #undef RNN_STEP

            float fa = (lane & 1) ? s1 : s0;
            float fb = (lane & 1) ? s0 : s1;
            fa += __shfl_xor(fb, 1);
            float fc = (lane & 1) ? s3 : s2;
            float fd = (lane & 1) ? s2 : s3;
            fc += __shfl_xor(fd, 1);
            float fe = (lane & 2) ? fc : fa;
            float ff = (lane & 2) ? fa : fc;
            fe += __shfl_xor(ff, 2);
            #pragma unroll
            for (int off = 4; off < 64; off <<= 1) fe += __shfl_xor(fe, off);
            sv = fe;
        }

        // lanes 0-3 hold valid sums; f32 h, RNE-round to bf16, pair-merge
        float hn = fast_tanh(sv + xq);
        unsigned ub = __float_as_uint(hn);
        unsigned b16 = (ub + 0x7fffu + ((ub >> 16) & 1u)) >> 16;
        unsigned partner = (unsigned)__shfl_xor((int)b16, 1);   // lane0<-1, lane2<-3

        if (lane < 4) {
            if ((lane & 1) == 0) {
                // granule g = r0/4 = b*8+wid, word (lane>>1); own 64B line
                u64 pk = ((u64)(unsigned)(t + 1) << 32)
                       | ((u64)(partner & 0xffffu) << 16) | (u64)(b16 & 0xffffu);
                (void)__hip_atomic_exchange(
                    &hbuf[(size_t)((t + 1) & 1) * HB_STRIDE
                          + (size_t)(r0 >> 2) * 8 + (lane >> 1)],
                    pk, __ATOMIC_RELAXED, __HIP_MEMORY_SCOPE_AGENT);
            }
            Hs[(size_t)t * HDIM + r0 + lane] = hn;   // f32, consumed by GEMM-3
        }
    }
}

// ---------------------------------------------------------------------------
// Row softmax over EDIM=2048: one block (256 threads) per row.
// ---------------------------------------------------------------------------
__global__ __launch_bounds__(256) void softmax_rows(
    const float* __restrict__ logits, float* __restrict__ out)
{
    const int row = blockIdx.x;
    const float4* in4 = (const float4*)(logits + (size_t)row * EDIM);
    float4* out4 = (float4*)(out + (size_t)row * EDIM);

    float4 v0 = in4[threadIdx.x];
    float4 v1 = in4[threadIdx.x + 256];

    float m = fmaxf(fmaxf(fmaxf(v0.x, v0.y), fmaxf(v0.z, v0.w)),
                    fmaxf(fmaxf(v1.x, v1.y), fmaxf(v1.z, v1.w)));
    #pragma unroll
    for (int off = 32; off > 0; off >>= 1) m = fmaxf(m, __shfl_xor(m, off));

    __shared__ float red[4];
    if ((threadIdx.x & 63) == 0) red[threadIdx.x >> 6] = m;
    __syncthreads();
    m = fmaxf(fmaxf(red[0], red[1]), fmaxf(red[2], red[3]));
    __syncthreads();

    float e[8];
    e[0] = expf(v0.x - m); e[1] = expf(v0.y - m);
    e[2] = expf(v0.z - m); e[3] = expf(v0.w - m);
    e[4] = expf(v1.x - m); e[5] = expf(v1.y - m);
    e[6] = expf(v1.z - m); e[7] = expf(v1.w - m);

    float s = e[0] + e[1] + e[2] + e[3] + e[4] + e[5] + e[6] + e[7];
    #pragma unroll
    for (int off = 32; off > 0; off >>= 1) s += __shfl_xor(s, off);
    if ((threadIdx.x & 63) == 0) red[threadIdx.x >> 6] = s;
    __syncthreads();
    s = red[0] + red[1] + red[2] + red[3];

    float inv = 1.0f / s;
    out4[threadIdx.x]       = make_float4(e[0] * inv, e[1] * inv, e[2] * inv, e[3] * inv);
    out4[threadIdx.x + 256] = make_float4(e[4] * inv, e[5] * inv, e[6] * inv, e[7] * inv);
}

__global__ void copy_vec(const float* __restrict__ src, float* __restrict__ dst, int n)
{
    int i = blockIdx.x * blockDim.x + threadIdx.x;
    if (i < n) dst[i] = src[i];
}

// ---------------------------------------------------------------------------
extern "C" void kernel_launch(void* const* d_in, const int* in_sizes, int n_in,
                              void* d_out, int out_size, void* d_ws, size_t ws_size,
                              hipStream_t stream)
{
    const float* x  = (const float*)d_in[0];   // [T_SEQ][EDIM]
    const float* Wh = (const float*)d_in[1];   // [HDIM][HDIM]
    const float* Wx = (const float*)d_in[2];   // [HDIM][EDIM]
    const float* Wy = (const float*)d_in[3];   // [EDIM][HDIM]
    const float* Bh = (const float*)d_in[4];   // [HDIM]
    const float* By = (const float*)d_in[5];   // [EDIM]

    float* out    = (float*)d_out;
    float* hfinal = out;                 // [HDIM]
    float* hs     = out + HDIM;          // [T_SEQ][HDIM]: holds hs, then probs

    float* xpT  = (float*)d_ws;                                   // [HDIM][T_SEQ]
    u64*   hbuf = (u64*)((char*)d_ws + (size_t)T_SEQ * HDIM * 4); // [2][HB_STRIDE]
    float* logits = xpT;                 // reuse (xpT dead after recurrence)

    // clear tagged h buffers so replays never see stale tags
    hipMemsetAsync(hbuf, 0, 2 * HB_STRIDE * sizeof(u64), stream);

    // Phase 1: xpT = (x @ Wx^T + Bh)^T   -> [HDIM][T_SEQ]
    gemm128_nt_bias_tc<<<dim3(HDIM / 128, T_SEQ / 128), 256, 0, stream>>>(
        x, Wx, Bh, xpT, T_SEQ, HDIM, EDIM);

    // Phase 2: recurrence — cooperative launch only to guarantee co-residency
    int T = T_SEQ;
    const float* xpT_c = xpT;
    void* args[] = {(void*)&Wh, (void*)&xpT_c, (void*)&hs, (void*)&hbuf, (void*)&T};
    hipLaunchCooperativeKernel((void*)rnn_recurrence, dim3(RBLK), dim3(512),
                               args, 0, stream);

    // Phase 3: logits = hs @ Wy^T + By   (normal [T][E] layout)
    gemm128_nt_bias<<<dim3(EDIM / 128, T_SEQ / 128), 256, 0, stream>>>(
        hs, Wy, By, logits, T_SEQ, EDIM, HDIM);

    // Phase 4: h_final = hs[T-1] (before softmax overwrites hs region)
    copy_vec<<<dim3(HDIM / 256), 256, 0, stream>>>(
        hs + (size_t)(T_SEQ - 1) * HDIM, hfinal, HDIM);

    // Phase 5: softmax rows: logits (ws) -> output region of d_out
    softmax_rows<<<dim3(T_SEQ), 256, 0, stream>>>(logits, hs);
}